// Round 3
// baseline (24.593 us; speedup 1.0000x reference)
//
#include <hip/hip_runtime.h>

// Problem constants: B=2048, D=2048, H=16, Q=128, N=8192, V=128
// Identity: softmax rows sum to 1 => attn_rowsum == 1, so
//   out[b,:] = x[b,:] + c,  c[d] = sum_k vmean[k & 127] * Wo[d, k]
//           = dot(vmean, WoF[d,:]),  WoF[d,v] = sum_h Wo[d, h*128+v].
// 2 dispatches:
//   K1 (1024 blocks): blocks 0..127 -> values column partial-sums;
//                     blocks 128..1023 -> WoF head-fold (independent of values).
//   K2 (1024 blocks = 64 row-groups x 16 d-chunks): per-block redundant
//       vmean reduce (64 KB L2) + c-chunk via WoF slice (64 KB L2), then
//       stream out = x + c for its 32-row x 128-col tile.

#define NROWS 8192
#define VDIM  128
#define DDIM  2048
#define BDIM  2048
#define P_ROWS 128       // partial rows written by K1's values half

// ---------------------------------------------------------------------------
// K1: fused values-colsum partials + Wo head-fold.
__global__ void prep_kernel(const float4* __restrict__ vals4,
                            const float4* __restrict__ Wo4,
                            float4* __restrict__ partial4,   // [128][32] f4
                            float4* __restrict__ WoF4) {     // [2048][32] f4
    __shared__ float4 s[256];
    const int t = threadIdx.x;
    const int b = blockIdx.x;

    if (b < P_ROWS) {
        // values colsum: rows [b*64, b*64+64): 2048 f4, col-quad (t&31) invariant
        float4 acc = make_float4(0.f, 0.f, 0.f, 0.f);
        const int base = b * 2048;
#pragma unroll
        for (int j = 0; j < 8; ++j) {
            float4 v = vals4[base + t + 256 * j];
            acc.x += v.x; acc.y += v.y; acc.z += v.z; acc.w += v.w;
        }
        s[t] = acc;
        __syncthreads();
        if (t < 32) {
            float4 r = s[t];
#pragma unroll
            for (int k = 1; k < 8; ++k) {
                float4 v = s[t + 32 * k];
                r.x += v.x; r.y += v.y; r.z += v.z; r.w += v.w;
            }
            partial4[b * 32 + t] = r;
        }
    } else {
        // WoF fold: rows d = wb, wb+896, wb+1792 (<2048)
        const int wb = b - P_ROWS;  // 0..895
        const int vq = t & 31;      // v quad
        const int hg = t >> 5;      // 0..7, handles h = 2*hg, 2*hg+1
        for (int d = wb; d < DDIM; d += 896) {
            const float4* row = Wo4 + (size_t)d * 512;
            float4 a = row[(2 * hg) * 32 + vq];
            float4 c = row[(2 * hg + 1) * 32 + vq];
            a.x += c.x; a.y += c.y; a.z += c.z; a.w += c.w;
            s[t] = a;
            __syncthreads();
            if (t < 32) {
                float4 r = s[t];
#pragma unroll
                for (int k = 1; k < 8; ++k) {
                    float4 v = s[t + 32 * k];
                    r.x += v.x; r.y += v.y; r.z += v.z; r.w += v.w;
                }
                WoF4[d * 32 + t] = r;
            }
            __syncthreads();
        }
    }
}

// ---------------------------------------------------------------------------
// K2: per-block c-chunk + streaming add.
// grid 1024: dc = bid & 15 (d range dc*128..+128), rg = bid >> 4 (rows rg*32..+32)
__global__ void c_add_kernel(const float4* __restrict__ partial4,
                             const float4* __restrict__ WoF4,
                             const float4* __restrict__ x4,
                             float4* __restrict__ out4) {
    __shared__ float4 s[256];
    __shared__ float4 vm_lds[32];
    __shared__ float  c_lds[128];
    const int t = threadIdx.x;
    const int dc = blockIdx.x & 15;
    const int rg = blockIdx.x >> 4;

    // (1) redundant vmean reduce: partial [128][32] f4 = 4096 f4, L2-resident
    float4 acc = make_float4(0.f, 0.f, 0.f, 0.f);
#pragma unroll
    for (int j = 0; j < 16; ++j) {
        float4 v = partial4[t + 256 * j];  // col-quad (t&31) invariant
        acc.x += v.x; acc.y += v.y; acc.z += v.z; acc.w += v.w;
    }
    s[t] = acc;
    __syncthreads();
    if (t < 32) {
        float4 r = s[t];
#pragma unroll
        for (int k = 1; k < 8; ++k) {
            float4 v = s[t + 32 * k];
            r.x += v.x; r.y += v.y; r.z += v.z; r.w += v.w;
        }
        const float inv = 1.0f / (float)NROWS;
        r.x *= inv; r.y *= inv; r.z *= inv; r.w *= inv;
        vm_lds[t] = r;
    }
    __syncthreads();

    // (2) c-chunk: 128 d's, 2 threads per d (half-rows), shfl-pair reduce
    {
        const int ld = t >> 1;       // 0..127 local d
        const int half = t & 1;      // which 16-f4 half
        const size_t base = (size_t)(dc * 128 + ld) * 32 + half * 16;
        float dot = 0.f;
#pragma unroll
        for (int j = 0; j < 16; ++j) {
            float4 w = WoF4[base + j];
            float4 vm = vm_lds[half * 16 + j];
            dot += w.x * vm.x + w.y * vm.y + w.z * vm.z + w.w * vm.w;
        }
        dot += __shfl_xor(dot, 1);
        if (half == 0) c_lds[ld] = dot;
    }
    __syncthreads();

    // (3) stream out = x + c for rows [rg*32, +32), cols [dc*128, +128)
    const float4* __restrict__ c4 = (const float4*)c_lds;
    const int q = t & 31;            // f4 col within chunk
    const int r0 = rg * 32 + (t >> 5);  // 8 rows per iter
    const float4 cv = c4[q];
#pragma unroll
    for (int i = 0; i < 4; ++i) {
        const int r = r0 + i * 8;
        const size_t idx = (size_t)r * 512 + dc * 32 + q;
        float4 xv = x4[idx];
        xv.x += cv.x; xv.y += cv.y; xv.z += cv.z; xv.w += cv.w;
        out4[idx] = xv;
    }
}

// ---------------------------------------------------------------------------
extern "C" void kernel_launch(void* const* d_in, const int* in_sizes, int n_in,
                              void* d_out, int out_size, void* d_ws, size_t ws_size,
                              hipStream_t stream) {
    // inputs: 0=x [B,D], 1=keys (unused), 2=values [N,V], 3=Wq (unused), 4=Wo [D,H*V]
    const float* x      = (const float*)d_in[0];
    const float* values = (const float*)d_in[2];
    const float* Wo     = (const float*)d_in[4];
    float* out = (float*)d_out;
    float* ws  = (float*)d_ws;

    float4* partial4 = (float4*)ws;                     // 128*32 f4 = 64 KB
    float4* WoF4     = (float4*)(ws + P_ROWS * VDIM);   // 2048*32 f4 = 1 MB

    prep_kernel<<<1024, 256, 0, stream>>>((const float4*)values, (const float4*)Wo,
                                          partial4, WoF4);
    c_add_kernel<<<1024, 256, 0, stream>>>(partial4, WoF4,
                                           (const float4*)x, (float4*)out);
}